// Round 4
// baseline (714.449 us; speedup 1.0000x reference)
//
#include <hip/hip_runtime.h>
#include <hip/hip_bf16.h>

// 5-layer GCN: widths 128 -> 128/64/32/16/8, N=100000 nodes, E=1600000 edges.
// R14: 8-FEAT SLICES + SLICE-TEMPORAL XCD SCHEDULING — aggr is bound by the
//      L2-miss fill path (335 MB @ ~3 TB/s); ~230 MB are capacity re-fetches
//      (16-feat slice set 6.4 MB/XCD > 4 MB L2). g re-blocked [f/8][N][8]
//      (32 B/node/slice -> 3.2 MB/slice fits L2). Grid is group-major
//      (8 slices per temporal group, sl = grp*8 + b%8) so each XCD works ONE
//      slice at a time. No partials, no barrier (R11/R13 lessons: partial
//      round-trips cost what they save; intra-block phasing drifts).
//      CSR reverted to single-bucket (R13's 2-seg split cost +8 µs loop
//      overhead, FETCH unchanged -> refuted).
// R12: 8x8 register micro-tile GEMM (kept; blocked8 IO now).
// R9:  LDS-staged CSR indices. R8: regular g store (L2-resident for aggr).
// R3:  XCD-range-partitioned CSR build.

#define SCAN_B 1024
#define LDSE   4096   // aggr: staged edge indices (16 KB), 128 nodes/block

typedef float floatx4 __attribute__((ext_vector_type(4)));

// ---------------- ranged degree histogram ----------------
__global__ __launch_bounds__(256) void k_count_r(const int* __restrict__ dst,
                                                 int* __restrict__ deg, int E, int N) {
    const int r  = blockIdx.x % 8;
    const int lo = (int)((long long)r * N / 8);
    const int hi = (int)((long long)(r + 1) * N / 8);
    const int nb = gridDim.x / 8;
    const int jb = blockIdx.x / 8;
    const int stride = nb * 256;
    for (int e = jb * 256 + threadIdx.x; e < E; e += stride) {
        int d = __builtin_nontemporal_load(&dst[e]);
        if (d >= lo && d < hi) atomicAdd(&deg[d], 1);
    }
}

// ---------------- exclusive scan (3 kernels) ----------------
__global__ void k_scan_block(const int* __restrict__ deg, int* __restrict__ out,
                             int* __restrict__ sums, int n) {
    __shared__ int tmp[SCAN_B];
    int i = blockIdx.x * SCAN_B + threadIdx.x;
    int v = (i < n) ? deg[i] : 0;
    tmp[threadIdx.x] = v;
    __syncthreads();
    for (int off = 1; off < SCAN_B; off <<= 1) {
        int t = (threadIdx.x >= off) ? tmp[threadIdx.x - off] : 0;
        __syncthreads();
        tmp[threadIdx.x] += t;
        __syncthreads();
    }
    if (i < n) out[i] = tmp[threadIdx.x] - v;   // exclusive within block
    if (threadIdx.x == SCAN_B - 1) sums[blockIdx.x] = tmp[threadIdx.x];
}

__global__ void k_scan_sums(int* __restrict__ sums, int nb) {
    __shared__ int tmp[128];
    int v = (threadIdx.x < nb) ? sums[threadIdx.x] : 0;
    tmp[threadIdx.x] = v;
    __syncthreads();
    for (int off = 1; off < 128; off <<= 1) {
        int t = (threadIdx.x >= off) ? tmp[threadIdx.x - off] : 0;
        __syncthreads();
        tmp[threadIdx.x] += t;
        __syncthreads();
    }
    if (threadIdx.x < nb) sums[threadIdx.x] = tmp[threadIdx.x] - v;  // exclusive
}

__global__ void k_finalize(int* __restrict__ offsets, const int* __restrict__ sums,
                           const int* __restrict__ deg, int* __restrict__ cursor,
                           float* __restrict__ dinv, int n, int E) {
    int i = blockIdx.x * blockDim.x + threadIdx.x;
    if (i < n) {
        int off = offsets[i] + sums[i / SCAN_B];
        offsets[i] = off;
        cursor[i]  = off;
        dinv[i]    = rsqrtf((float)(deg[i] + 1));   // +1 self loop
    }
    if (i == 0) offsets[n] = E;
}

// ---------------- ranged CSR bucket fill ----------------
__global__ __launch_bounds__(256) void k_fill_r(const int* __restrict__ src,
                                                const int* __restrict__ dst,
                                                int* __restrict__ cursor,
                                                int* __restrict__ csr_src, int E, int N) {
    const int r  = blockIdx.x % 8;
    const int lo = (int)((long long)r * N / 8);
    const int hi = (int)((long long)(r + 1) * N / 8);
    const int nb = gridDim.x / 8;
    const int jb = blockIdx.x / 8;
    const int stride = nb * 256;
    for (int e = jb * 256 + threadIdx.x; e < E; e += stride) {
        int d = __builtin_nontemporal_load(&dst[e]);
        if (d >= lo && d < hi) {
            int pos = atomicAdd(&cursor[d], 1);
            csr_src[pos] = __builtin_nontemporal_load(&src[e]);
        }
    }
}

// ---------------- register-blocked GEMM (NR x NC micro-tile) ----------------
// IO layout blocked8: g[f/8][n][8]. Input: BIN -> blocked8; else row-major.
// Wl layout [fg][k][NC] pitch WP = KC*NC+4 dwords (WP%32==4): W reads <=2-way
// bank aliased (free). xt [k][m] with MP=M+4: x reads are group broadcasts.
template <int FIN, int FOUT, int NR, int NC, bool BIN>
__global__ __launch_bounds__(256) void k_gemm(const float* __restrict__ x,
                                              const float* __restrict__ W,
                                              const float* __restrict__ dinv,
                                              float* __restrict__ g, int n) {
    constexpr int NFG = FOUT / NC;            // fo-groups per block
    constexpr int M   = NR * (256 / NFG);     // nodes per block
    constexpr int KC  = (FIN < 32) ? FIN : 32;
    constexpr int MP  = M + 4;
    constexpr int WP  = KC * NC + 4;          // pitch in dwords, %32 == 4
    __shared__ float Wl[NFG * WP];
    __shared__ float xt[KC * MP];

    const int tid = threadIdx.x;
    const int fg  = tid % NFG;
    const int mg  = tid / NFG;
    const int m0  = blockIdx.x * M;
    const floatx4* x4 = reinterpret_cast<const floatx4*>(x);

    float acc[NR][NC];
#pragma unroll
    for (int i = 0; i < NR; ++i)
#pragma unroll
        for (int j = 0; j < NC; ++j) acc[i][j] = 0.f;

    for (int kc0 = 0; kc0 < FIN; kc0 += KC) {
        __syncthreads();
        for (int idx = tid; idx < KC * FOUT; idx += 256) {
            int k  = idx / FOUT;
            int fo = idx % FOUT;
            Wl[(fo / NC) * WP + k * NC + (fo % NC)] = W[(kc0 + k) * FOUT + fo];
        }
        constexpr int SLOTS = KC / 4;           // float4 slots per node per chunk
        for (int s = tid; s < M * SLOTS; s += 256) {
            int ml    = s / SLOTS;
            int slot  = s % SLOTS;
            int gslot = kc0 / 4 + slot;
            int gn    = m0 + ml;
            floatx4 v = (floatx4)(0.f);
            if (gn < n) {
                size_t idx2 = BIN ? (((size_t)(gslot >> 1) * n + gn) * 2 + (gslot & 1))
                                  : ((size_t)gn * (FIN / 4) + gslot);
                v = __builtin_nontemporal_load(&x4[idx2]);
            }
            xt[(slot * 4 + 0) * MP + ml] = v.x;
            xt[(slot * 4 + 1) * MP + ml] = v.y;
            xt[(slot * 4 + 2) * MP + ml] = v.z;
            xt[(slot * 4 + 3) * MP + ml] = v.w;
        }
        __syncthreads();
#pragma unroll 4
        for (int k = 0; k < KC; ++k) {
            float xr[NR], wr[NC];
#pragma unroll
            for (int p = 0; p < NR / 4; ++p) {
                float4 v = *reinterpret_cast<const float4*>(&xt[k * MP + mg * NR + p * 4]);
                xr[p * 4 + 0] = v.x; xr[p * 4 + 1] = v.y;
                xr[p * 4 + 2] = v.z; xr[p * 4 + 3] = v.w;
            }
#pragma unroll
            for (int p = 0; p < NC / 4; ++p) {
                float4 v = *reinterpret_cast<const float4*>(&Wl[fg * WP + k * NC + p * 4]);
                wr[p * 4 + 0] = v.x; wr[p * 4 + 1] = v.y;
                wr[p * 4 + 2] = v.z; wr[p * 4 + 3] = v.w;
            }
#pragma unroll
            for (int i = 0; i < NR; ++i)
#pragma unroll
                for (int j = 0; j < NC; ++j) acc[i][j] += xr[i] * wr[j];
        }
    }

    float4* g4 = reinterpret_cast<float4*>(g);
#pragma unroll
    for (int i = 0; i < NR; ++i) {
        int gn = m0 + mg * NR + i;
        if (gn < n) {
            float d = dinv[gn];
#pragma unroll
            for (int p = 0; p < NC / 4; ++p) {
                float4 o = make_float4(acc[i][p * 4 + 0] * d, acc[i][p * 4 + 1] * d,
                                       acc[i][p * 4 + 2] * d, acc[i][p * 4 + 3] * d);
                int slot = (fg * NC) / 4 + p;
                g4[((size_t)(slot >> 1) * n + gn) * 2 + (slot & 1)] = o;
            }
        }
    }
}

// ---------------- 8-feature-slice CSR aggregation (all layers) ----------------
// g blocked8 [f/8][N][8]: 32 B/node/slice, 2 lanes/node, 128 nodes/block.
// Grid is GROUP-MAJOR: 8 slices per temporal group, sl = grp*8 + (b%gsz), so
// XCD k (block b -> XCD b%8) processes ONE 3.2 MB slice at a time (fits the
// 4 MB per-XCD L2 -> capacity re-fetches eliminated). nsl=1 == layer-5 path.
__global__ __launch_bounds__(256) void k_aggr(const float4* __restrict__ gb,
                                              const int* __restrict__ offsets,
                                              const int* __restrict__ csr_src,
                                              const float* __restrict__ dinv,
                                              const float* __restrict__ bias,
                                              float4* __restrict__ outb,
                                              int n, int nsl, int nbB) {
    __shared__ int eidx[LDSE];
    const int gsz     = (nsl < 8) ? nsl : 8;   // slices per temporal group
    const int gblocks = gsz * nbB;
    const int grp     = blockIdx.x / gblocks;
    const int bl      = blockIdx.x % gblocks;
    const int sl      = grp * 8 + (bl % gsz);
    const int nb      = bl / gsz;

    const int node0  = nb * 128;
    const int nodeHi = (node0 + 128 < n) ? node0 + 128 : n;
    const int node   = node0 + (threadIdx.x >> 1);
    const int h      = threadIdx.x & 1;

    const int eS = offsets[node0];
    const int eE = offsets[nodeHi];
    const int C  = eE - eS;
    const bool useLds = (C <= LDSE);

    const bool alive = (node < n);
    int e0 = 0, e1 = 0;
    float dnode = 0.f;
    const float4* gs = gb + (size_t)sl * n * 2;
    float4 a0 = make_float4(0.f, 0.f, 0.f, 0.f);
    if (alive) {
        e0 = offsets[node];
        e1 = offsets[node + 1];
        dnode = dinv[node];
        a0 = gs[(size_t)node * 2 + h];            // self-loop term
    }

    if (useLds) {
        for (int i = threadIdx.x; i < C; i += 256)
            eidx[i] = __builtin_nontemporal_load(&csr_src[eS + i]);
    }
    __syncthreads();
    if (!alive) return;

    float4 a1 = make_float4(0.f, 0.f, 0.f, 0.f);
    float4 a2 = a1, a3 = a1;

    const int m = e1 - e0;
    int i = 0;
    if (useLds) {
        const int le = e0 - eS;
        for (; i + 8 <= m; i += 8) {
            int s0 = eidx[le + i + 0], s1 = eidx[le + i + 1];
            int s2 = eidx[le + i + 2], s3 = eidx[le + i + 3];
            int s4 = eidx[le + i + 4], s5 = eidx[le + i + 5];
            int s6 = eidx[le + i + 6], s7 = eidx[le + i + 7];
            float4 v0 = gs[(size_t)s0 * 2 + h], v1 = gs[(size_t)s1 * 2 + h];
            float4 v2 = gs[(size_t)s2 * 2 + h], v3 = gs[(size_t)s3 * 2 + h];
            float4 v4 = gs[(size_t)s4 * 2 + h], v5 = gs[(size_t)s5 * 2 + h];
            float4 v6 = gs[(size_t)s6 * 2 + h], v7 = gs[(size_t)s7 * 2 + h];
            a0.x += v0.x; a0.y += v0.y; a0.z += v0.z; a0.w += v0.w;
            a1.x += v1.x; a1.y += v1.y; a1.z += v1.z; a1.w += v1.w;
            a2.x += v2.x; a2.y += v2.y; a2.z += v2.z; a2.w += v2.w;
            a3.x += v3.x; a3.y += v3.y; a3.z += v3.z; a3.w += v3.w;
            a0.x += v4.x; a0.y += v4.y; a0.z += v4.z; a0.w += v4.w;
            a1.x += v5.x; a1.y += v5.y; a1.z += v5.z; a1.w += v5.w;
            a2.x += v6.x; a2.y += v6.y; a2.z += v6.z; a2.w += v6.w;
            a3.x += v7.x; a3.y += v7.y; a3.z += v7.z; a3.w += v7.w;
        }
        for (; i + 4 <= m; i += 4) {
            int s0 = eidx[le + i + 0], s1 = eidx[le + i + 1];
            int s2 = eidx[le + i + 2], s3 = eidx[le + i + 3];
            float4 v0 = gs[(size_t)s0 * 2 + h], v1 = gs[(size_t)s1 * 2 + h];
            float4 v2 = gs[(size_t)s2 * 2 + h], v3 = gs[(size_t)s3 * 2 + h];
            a0.x += v0.x; a0.y += v0.y; a0.z += v0.z; a0.w += v0.w;
            a1.x += v1.x; a1.y += v1.y; a1.z += v1.z; a1.w += v1.w;
            a2.x += v2.x; a2.y += v2.y; a2.z += v2.z; a2.w += v2.w;
            a3.x += v3.x; a3.y += v3.y; a3.z += v3.z; a3.w += v3.w;
        }
        for (; i < m; ++i) {
            float4 v = gs[(size_t)eidx[le + i] * 2 + h];
            a0.x += v.x; a0.y += v.y; a0.z += v.z; a0.w += v.w;
        }
    } else {
        for (; i + 4 <= m; i += 4) {
            int s0 = csr_src[e0 + i + 0], s1 = csr_src[e0 + i + 1];
            int s2 = csr_src[e0 + i + 2], s3 = csr_src[e0 + i + 3];
            float4 v0 = gs[(size_t)s0 * 2 + h], v1 = gs[(size_t)s1 * 2 + h];
            float4 v2 = gs[(size_t)s2 * 2 + h], v3 = gs[(size_t)s3 * 2 + h];
            a0.x += v0.x; a0.y += v0.y; a0.z += v0.z; a0.w += v0.w;
            a1.x += v1.x; a1.y += v1.y; a1.z += v1.z; a1.w += v1.w;
            a2.x += v2.x; a2.y += v2.y; a2.z += v2.z; a2.w += v2.w;
            a3.x += v3.x; a3.y += v3.y; a3.z += v3.z; a3.w += v3.w;
        }
        for (; i < m; ++i) {
            float4 v = gs[(size_t)csr_src[e0 + i] * 2 + h];
            a0.x += v.x; a0.y += v.y; a0.z += v.z; a0.w += v.w;
        }
    }
    a0.x += a1.x + a2.x + a3.x;
    a0.y += a1.y + a2.y + a3.y;
    a0.z += a1.z + a2.z + a3.z;
    a0.w += a1.w + a2.w + a3.w;

    const float* bf = bias + sl * 8 + h * 4;
    floatx4 r;
    r.x = fmaxf(dnode * a0.x + bf[0], 0.f);
    r.y = fmaxf(dnode * a0.y + bf[1], 0.f);
    r.z = fmaxf(dnode * a0.z + bf[2], 0.f);
    r.w = fmaxf(dnode * a0.w + bf[3], 0.f);
    floatx4* ob = reinterpret_cast<floatx4*>(outb);
    __builtin_nontemporal_store(r, &ob[((size_t)sl * n + node) * 2 + h]);
}

extern "C" void kernel_launch(void* const* d_in, const int* in_sizes, int n_in,
                              void* d_out, int out_size, void* d_ws, size_t ws_size,
                              hipStream_t stream) {
    const int N = in_sizes[0] / 128;
    const int E = in_sizes[1] / 2;

    const float* x   = (const float*)d_in[0];
    const int*   ei  = (const int*)d_in[1];
    const int*   src = ei;
    const int*   dst = ei + E;
    const float* W1 = (const float*)d_in[2],  *b1 = (const float*)d_in[3];
    const float* W2 = (const float*)d_in[4],  *b2 = (const float*)d_in[5];
    const float* W3 = (const float*)d_in[6],  *b3 = (const float*)d_in[7];
    const float* W4 = (const float*)d_in[8],  *b4 = (const float*)d_in[9];
    const float* W5 = (const float*)d_in[10], *b5 = (const float*)d_in[11];
    float* out = (float*)d_out;

    size_t off = 0;
    auto alloc = [&](size_t bytes) {
        void* p = (char*)d_ws + off;
        off += (bytes + 255) & ~(size_t)255;
        return p;
    };
    int*   deg     = (int*)alloc((size_t)N * 4);
    int*   offsets = (int*)alloc((size_t)(N + 1) * 4);
    int*   cursor  = (int*)alloc((size_t)N * 4);
    int*   sums    = (int*)alloc(128 * 4);
    float* dinv    = (float*)alloc((size_t)N * 4);
    int*   csr_src = (int*)alloc((size_t)E * 4);
    float* g       = (float*)alloc((size_t)N * 128 * 4);
    float* xbuf    = (float*)alloc((size_t)N * 128 * 4);

    (void)hipMemsetAsync(deg, 0, (size_t)N * 4, stream);

    const int TB = 256;
    int nb  = (N + SCAN_B - 1) / SCAN_B;
    int nbB = (N + 127) / 128;       // aggr: 128 nodes per block
    const int RG = 2048;             // ranged kernels: 256 blocks per dst-range

    k_count_r<<<RG, TB, 0, stream>>>(dst, deg, E, N);
    k_scan_block<<<nb, SCAN_B, 0, stream>>>(deg, offsets, sums, N);
    k_scan_sums<<<1, 128, 0, stream>>>(sums, nb);
    k_finalize<<<(N + TB - 1) / TB, TB, 0, stream>>>(offsets, sums, deg, cursor, dinv, N, E);
    k_fill_r<<<RG, TB, 0, stream>>>(src, dst, cursor, csr_src, E, N);

    const float4* g4  = (const float4*)g;
    float4*       xb4 = (float4*)xbuf;

    // Layer 1: 128 -> 128  (8x8 tile; 16 slice8s in 2 temporal groups)
    k_gemm<128, 128, 8, 8, false><<<(N + 127) / 128, TB, 0, stream>>>(x, W1, dinv, g, N);
    k_aggr<<<nbB * 16, TB, 0, stream>>>(g4, offsets, csr_src, dinv, b1, xb4, N, 16, nbB);
    // Layer 2: 128 -> 64  (8x8 tile; 8 slice8s, 1 group)
    k_gemm<128, 64, 8, 8, true><<<(N + 255) / 256, TB, 0, stream>>>(xbuf, W2, dinv, g, N);
    k_aggr<<<nbB * 8, TB, 0, stream>>>(g4, offsets, csr_src, dinv, b2, xb4, N, 8, nbB);
    // Layer 3: 64 -> 32  (8x4 tile; 4 slice8s)
    k_gemm<64, 32, 8, 4, true><<<(N + 255) / 256, TB, 0, stream>>>(xbuf, W3, dinv, g, N);
    k_aggr<<<nbB * 4, TB, 0, stream>>>(g4, offsets, csr_src, dinv, b3, xb4, N, 4, nbB);
    // Layer 4: 32 -> 16  (4x4 tile; 2 slice8s)
    k_gemm<32, 16, 4, 4, true><<<(N + 255) / 256, TB, 0, stream>>>(xbuf, W4, dinv, g, N);
    k_aggr<<<nbB * 2, TB, 0, stream>>>(g4, offsets, csr_src, dinv, b4, xb4, N, 2, nbB);
    // Layer 5: 16 -> 8  (4x4 tile; 1 slice8; writes d_out)
    k_gemm<16, 8, 4, 4, true><<<(N + 511) / 512, TB, 0, stream>>>(xbuf, W5, dinv, g, N);
    k_aggr<<<nbB * 1, TB, 0, stream>>>(g4, offsets, csr_src, dinv, b5, (float4*)out, N, 1, nbB);
}

// Round 5
// 546.453 us; speedup vs baseline: 1.3074x; 1.3074x over previous
//
#include <hip/hip_runtime.h>
#include <hip/hip_bf16.h>
#include <hip/hip_fp16.h>

// 5-layer GCN: widths 128 -> 128/64/32/16/8, N=100000 nodes, E=1600000 edges.
// R15: FP16 GATHER PAYLOAD (L1-3) — R14 proved aggr is NOT fill-bound
//      (FETCH 335->91 MB yet dur rose): it's request+delivery bound
//      (~2.9 us/M-line-requests + ~10 TB/s random delivery, fit from
//      R12/R14). Only lever: shrink payload. g stored fp16 in 32-feat
//      slices [f/32][N][32]h = 64 B/node/slice (full-line use, 4 lanes/node)
//      -> requests AND bytes halve. fp32 accumulation via __half22float2
//      (VALU is 20% busy — free). L4/L5 stay fp32 (small, no precision risk).
//      Residency/XCD-phasing abandoned for good (R11/R13/R14 refuted).
// R12: 8x8 register micro-tile GEMM; Wl pitch%32==4 (<=2-way bank alias).
// R10: full-64B-line gathers (the thing R14 broke and this restores).
// R9:  LDS-staged CSR indices. R8: regular g store. R3: ranged CSR build.

#define SCAN_B 1024
#define LDSE8  4096   // aggr8: staged edge indices (16 KB), 128 nodes/block
#define LDSE16 2048   // aggr16/aggrh: staged edge indices (8 KB), 64 nodes/block

typedef float floatx4 __attribute__((ext_vector_type(4)));

// ---------------- ranged degree histogram ----------------
__global__ __launch_bounds__(256) void k_count_r(const int* __restrict__ dst,
                                                 int* __restrict__ deg, int E, int N) {
    const int r  = blockIdx.x % 8;
    const int lo = (int)((long long)r * N / 8);
    const int hi = (int)((long long)(r + 1) * N / 8);
    const int nb = gridDim.x / 8;
    const int jb = blockIdx.x / 8;
    const int stride = nb * 256;
    for (int e = jb * 256 + threadIdx.x; e < E; e += stride) {
        int d = __builtin_nontemporal_load(&dst[e]);
        if (d >= lo && d < hi) atomicAdd(&deg[d], 1);
    }
}

// ---------------- exclusive scan (3 kernels) ----------------
__global__ void k_scan_block(const int* __restrict__ deg, int* __restrict__ out,
                             int* __restrict__ sums, int n) {
    __shared__ int tmp[SCAN_B];
    int i = blockIdx.x * SCAN_B + threadIdx.x;
    int v = (i < n) ? deg[i] : 0;
    tmp[threadIdx.x] = v;
    __syncthreads();
    for (int off = 1; off < SCAN_B; off <<= 1) {
        int t = (threadIdx.x >= off) ? tmp[threadIdx.x - off] : 0;
        __syncthreads();
        tmp[threadIdx.x] += t;
        __syncthreads();
    }
    if (i < n) out[i] = tmp[threadIdx.x] - v;   // exclusive within block
    if (threadIdx.x == SCAN_B - 1) sums[blockIdx.x] = tmp[threadIdx.x];
}

__global__ void k_scan_sums(int* __restrict__ sums, int nb) {
    __shared__ int tmp[128];
    int v = (threadIdx.x < nb) ? sums[threadIdx.x] : 0;
    tmp[threadIdx.x] = v;
    __syncthreads();
    for (int off = 1; off < 128; off <<= 1) {
        int t = (threadIdx.x >= off) ? tmp[threadIdx.x - off] : 0;
        __syncthreads();
        tmp[threadIdx.x] += t;
        __syncthreads();
    }
    if (threadIdx.x < nb) sums[threadIdx.x] = tmp[threadIdx.x] - v;  // exclusive
}

__global__ void k_finalize(int* __restrict__ offsets, const int* __restrict__ sums,
                           const int* __restrict__ deg, int* __restrict__ cursor,
                           float* __restrict__ dinv, int n, int E) {
    int i = blockIdx.x * blockDim.x + threadIdx.x;
    if (i < n) {
        int off = offsets[i] + sums[i / SCAN_B];
        offsets[i] = off;
        cursor[i]  = off;
        dinv[i]    = rsqrtf((float)(deg[i] + 1));   // +1 self loop
    }
    if (i == 0) offsets[n] = E;
}

// ---------------- ranged CSR bucket fill ----------------
__global__ __launch_bounds__(256) void k_fill_r(const int* __restrict__ src,
                                                const int* __restrict__ dst,
                                                int* __restrict__ cursor,
                                                int* __restrict__ csr_src, int E, int N) {
    const int r  = blockIdx.x % 8;
    const int lo = (int)((long long)r * N / 8);
    const int hi = (int)((long long)(r + 1) * N / 8);
    const int nb = gridDim.x / 8;
    const int jb = blockIdx.x / 8;
    const int stride = nb * 256;
    for (int e = jb * 256 + threadIdx.x; e < E; e += stride) {
        int d = __builtin_nontemporal_load(&dst[e]);
        if (d >= lo && d < hi) {
            int pos = atomicAdd(&cursor[d], 1);
            csr_src[pos] = __builtin_nontemporal_load(&src[e]);
        }
    }
}

// ---------------- register-blocked GEMM (NR x NC micro-tile) ----------------
// Input:  BIN -> fp32 blocked16 [fi/16][n][16]; else row-major [n][FIN].
// Output: HOUT -> fp16 blocked32 [fo/32][n][32]h;
//         else fp32: FOUT>=16 -> blocked16; FOUT==8 -> row-major [n][8].
template <int FIN, int FOUT, int NR, int NC, bool BIN, bool HOUT>
__global__ __launch_bounds__(256) void k_gemm(const float* __restrict__ x,
                                              const float* __restrict__ W,
                                              const float* __restrict__ dinv,
                                              float* __restrict__ g, int n) {
    constexpr int NFG = FOUT / NC;            // fo-groups per block
    constexpr int M   = NR * (256 / NFG);     // nodes per block
    constexpr int KC  = (FIN < 32) ? FIN : 32;
    constexpr int MP  = M + 4;
    constexpr int WP  = KC * NC + 4;          // pitch in dwords, %32 == 4
    __shared__ float Wl[NFG * WP];
    __shared__ float xt[KC * MP];

    const int tid = threadIdx.x;
    const int fg  = tid % NFG;
    const int mg  = tid / NFG;
    const int m0  = blockIdx.x * M;
    const floatx4* x4 = reinterpret_cast<const floatx4*>(x);

    float acc[NR][NC];
#pragma unroll
    for (int i = 0; i < NR; ++i)
#pragma unroll
        for (int j = 0; j < NC; ++j) acc[i][j] = 0.f;

    for (int kc0 = 0; kc0 < FIN; kc0 += KC) {
        __syncthreads();
        for (int idx = tid; idx < KC * FOUT; idx += 256) {
            int k  = idx / FOUT;
            int fo = idx % FOUT;
            Wl[(fo / NC) * WP + k * NC + (fo % NC)] = W[(kc0 + k) * FOUT + fo];
        }
        constexpr int SLOTS = KC / 4;           // float4 slots per node per chunk
        for (int s = tid; s < M * SLOTS; s += 256) {
            int ml    = s / SLOTS;
            int slot  = s % SLOTS;
            int gslot = kc0 / 4 + slot;
            int gn    = m0 + ml;
            floatx4 v = (floatx4)(0.f);
            if (gn < n) {
                size_t idx2 = BIN ? (((size_t)(gslot >> 2) * n + gn) * 4 + (gslot & 3))
                                  : ((size_t)gn * (FIN / 4) + gslot);
                v = __builtin_nontemporal_load(&x4[idx2]);
            }
            xt[(slot * 4 + 0) * MP + ml] = v.x;
            xt[(slot * 4 + 1) * MP + ml] = v.y;
            xt[(slot * 4 + 2) * MP + ml] = v.z;
            xt[(slot * 4 + 3) * MP + ml] = v.w;
        }
        __syncthreads();
#pragma unroll 4
        for (int k = 0; k < KC; ++k) {
            float xr[NR], wr[NC];
#pragma unroll
            for (int p = 0; p < NR / 4; ++p) {
                float4 v = *reinterpret_cast<const float4*>(&xt[k * MP + mg * NR + p * 4]);
                xr[p * 4 + 0] = v.x; xr[p * 4 + 1] = v.y;
                xr[p * 4 + 2] = v.z; xr[p * 4 + 3] = v.w;
            }
#pragma unroll
            for (int p = 0; p < NC / 4; ++p) {
                float4 v = *reinterpret_cast<const float4*>(&Wl[fg * WP + k * NC + p * 4]);
                wr[p * 4 + 0] = v.x; wr[p * 4 + 1] = v.y;
                wr[p * 4 + 2] = v.z; wr[p * 4 + 3] = v.w;
            }
#pragma unroll
            for (int i = 0; i < NR; ++i)
#pragma unroll
                for (int j = 0; j < NC; ++j) acc[i][j] += xr[i] * wr[j];
        }
    }

#pragma unroll
    for (int i = 0; i < NR; ++i) {
        int gn = m0 + mg * NR + i;
        if (gn < n) {
            float d = dinv[gn];
            if constexpr (HOUT) {
                if constexpr (NC == 8) {
                    // 8 halfs = 16 B: slice32 = fg>>2, float4 slot = fg&3
                    __half2 hv[4];
#pragma unroll
                    for (int p = 0; p < 4; ++p)
                        hv[p] = __floats2half2_rn(acc[i][2 * p] * d, acc[i][2 * p + 1] * d);
                    float4 o = *reinterpret_cast<float4*>(hv);
                    float4* gh4 = reinterpret_cast<float4*>(g);
                    gh4[(((size_t)(fg >> 2)) * n + gn) * 4 + (fg & 3)] = o;
                } else {
                    // NC==4 (FOUT==32, single slice32): 4 halfs = 8 B chunk fg of 64 B row
                    __half2 hv[2];
#pragma unroll
                    for (int p = 0; p < 2; ++p)
                        hv[p] = __floats2half2_rn(acc[i][2 * p] * d, acc[i][2 * p + 1] * d);
                    float2 o = *reinterpret_cast<float2*>(hv);
                    float2* gh2 = reinterpret_cast<float2*>(g);
                    gh2[(size_t)gn * 8 + fg] = o;
                }
            } else {
                float4* g4 = reinterpret_cast<float4*>(g);
#pragma unroll
                for (int p = 0; p < NC / 4; ++p) {
                    float4 o = make_float4(acc[i][p * 4 + 0] * d, acc[i][p * 4 + 1] * d,
                                           acc[i][p * 4 + 2] * d, acc[i][p * 4 + 3] * d);
                    int slot = (fg * NC) / 4 + p;
                    if constexpr (FOUT >= 16)
                        g4[((size_t)(slot >> 2) * n + gn) * 4 + (slot & 3)] = o;
                    else
                        g4[(size_t)gn * 2 + slot] = o;
                }
            }
        }
    }
}

// accumulate 8 fp16 feats (one float4 = 4 half2) into 8 fp32 accumulators
#define ACCUM8(A, v) {                                                        \
    union { float4 f; __half2 h[4]; } u_; u_.f = (v);                         \
    _Pragma("unroll")                                                         \
    for (int j_ = 0; j_ < 4; ++j_) {                                          \
        float2 f_ = __half22float2(u_.h[j_]);                                 \
        A[2 * j_] += f_.x; A[2 * j_ + 1] += f_.y;                             \
    } }

// ---------------- fp16 32-feat-slice CSR aggregation (layers 1-3) ----------
// g fp16 blocked32 [f/32][N][32]h: 64 B/node/slice, 4 lanes/node (full-line
// gathers). fp32 accumulation; writes fp32 blocked16 xbuf for the next GEMM.
__global__ __launch_bounds__(256) void k_aggrh(const float4* __restrict__ gh,
                                               const int* __restrict__ offsets,
                                               const int* __restrict__ csr_src,
                                               const float* __restrict__ dinv,
                                               const float* __restrict__ bias,
                                               float4* __restrict__ outb,
                                               int n, int nsl) {
    __shared__ int eidx[LDSE16];
    const int sl     = blockIdx.x % nsl;
    const int nb     = blockIdx.x / nsl;
    const int node0  = nb * 64;
    const int nodeHi = (node0 + 64 < n) ? node0 + 64 : n;
    const int node   = node0 + (threadIdx.x >> 2);
    const int q      = threadIdx.x & 3;

    const int eS = offsets[node0];
    const int eE = offsets[nodeHi];
    const int C  = eE - eS;
    const bool useLds = (C <= LDSE16);

    const bool alive = (node < n);
    int e0 = 0, e1 = 0;
    float dnode = 0.f;
    const float4* gs = gh + (size_t)sl * n * 4;   // 4 float4 (64 B) per node
    float A[8], B[8];
#pragma unroll
    for (int j = 0; j < 8; ++j) { A[j] = 0.f; B[j] = 0.f; }
    if (alive) {
        e0 = offsets[node];
        e1 = offsets[node + 1];
        dnode = dinv[node];
        float4 vs = gs[(size_t)node * 4 + q];     // self-loop term
        ACCUM8(A, vs);
    }

    if (useLds) {
        for (int i = threadIdx.x; i < C; i += 256)
            eidx[i] = __builtin_nontemporal_load(&csr_src[eS + i]);
    }
    __syncthreads();
    if (!alive) return;

    const int m = e1 - e0;
    int i = 0;
    if (useLds) {
        const int le = e0 - eS;
        for (; i + 4 <= m; i += 4) {
            int s0 = eidx[le + i + 0], s1 = eidx[le + i + 1];
            int s2 = eidx[le + i + 2], s3 = eidx[le + i + 3];
            float4 v0 = gs[(size_t)s0 * 4 + q], v1 = gs[(size_t)s1 * 4 + q];
            float4 v2 = gs[(size_t)s2 * 4 + q], v3 = gs[(size_t)s3 * 4 + q];
            ACCUM8(A, v0); ACCUM8(B, v1); ACCUM8(A, v2); ACCUM8(B, v3);
        }
        for (; i < m; ++i) {
            float4 v = gs[(size_t)eidx[le + i] * 4 + q];
            ACCUM8(A, v);
        }
    } else {
        for (; i + 4 <= m; i += 4) {
            int s0 = csr_src[e0 + i + 0], s1 = csr_src[e0 + i + 1];
            int s2 = csr_src[e0 + i + 2], s3 = csr_src[e0 + i + 3];
            float4 v0 = gs[(size_t)s0 * 4 + q], v1 = gs[(size_t)s1 * 4 + q];
            float4 v2 = gs[(size_t)s2 * 4 + q], v3 = gs[(size_t)s3 * 4 + q];
            ACCUM8(A, v0); ACCUM8(B, v1); ACCUM8(A, v2); ACCUM8(B, v3);
        }
        for (; i < m; ++i) {
            float4 v = gs[(size_t)csr_src[e0 + i] * 4 + q];
            ACCUM8(A, v);
        }
    }

    const float* bf = bias + sl * 32 + q * 8;
    floatx4 r0, r1;
    r0.x = fmaxf(dnode * (A[0] + B[0]) + bf[0], 0.f);
    r0.y = fmaxf(dnode * (A[1] + B[1]) + bf[1], 0.f);
    r0.z = fmaxf(dnode * (A[2] + B[2]) + bf[2], 0.f);
    r0.w = fmaxf(dnode * (A[3] + B[3]) + bf[3], 0.f);
    r1.x = fmaxf(dnode * (A[4] + B[4]) + bf[4], 0.f);
    r1.y = fmaxf(dnode * (A[5] + B[5]) + bf[5], 0.f);
    r1.z = fmaxf(dnode * (A[6] + B[6]) + bf[6], 0.f);
    r1.w = fmaxf(dnode * (A[7] + B[7]) + bf[7], 0.f);
    // fp32 blocked16 xbuf: f16blk = sl*2 + (q>>1), float4 slots (q&1)*2 + {0,1}
    floatx4* ob = reinterpret_cast<floatx4*>(outb);
    size_t base = ((size_t)(sl * 2 + (q >> 1)) * n + node) * 4 + (q & 1) * 2;
    __builtin_nontemporal_store(r0, &ob[base + 0]);
    __builtin_nontemporal_store(r1, &ob[base + 1]);
}

// ---------------- fp32 16-feature-slice CSR aggregation (layer 4) ----------
__global__ __launch_bounds__(256) void k_aggr16(const float4* __restrict__ gb,
                                                const int* __restrict__ offsets,
                                                const int* __restrict__ csr_src,
                                                const float* __restrict__ dinv,
                                                const float* __restrict__ bias,
                                                float4* __restrict__ outb,
                                                int n, int nsl) {
    __shared__ int eidx[LDSE16];
    const int sl     = blockIdx.x % nsl;
    const int nb     = blockIdx.x / nsl;
    const int node0  = nb * 64;
    const int nodeHi = (node0 + 64 < n) ? node0 + 64 : n;
    const int node   = node0 + (threadIdx.x >> 2);
    const int q      = threadIdx.x & 3;

    const int eS = offsets[node0];
    const int eE = offsets[nodeHi];
    const int C  = eE - eS;
    const bool useLds = (C <= LDSE16);

    const bool alive = (node < n);
    int e0 = 0, e1 = 0;
    float dnode = 0.f;
    const float4* gs = gb + (size_t)sl * n * 4;
    float4 a0 = make_float4(0.f, 0.f, 0.f, 0.f);
    if (alive) {
        e0 = offsets[node];
        e1 = offsets[node + 1];
        dnode = dinv[node];
        a0 = gs[(size_t)node * 4 + q];            // self-loop term
    }

    if (useLds) {
        for (int i = threadIdx.x; i < C; i += 256)
            eidx[i] = __builtin_nontemporal_load(&csr_src[eS + i]);
    }
    __syncthreads();
    if (!alive) return;

    float4 a1 = make_float4(0.f, 0.f, 0.f, 0.f);
    float4 a2 = a1, a3 = a1;

    const int m = e1 - e0;
    int i = 0;
    if (useLds) {
        const int le = e0 - eS;
        for (; i + 4 <= m; i += 4) {
            int s0 = eidx[le + i + 0], s1 = eidx[le + i + 1];
            int s2 = eidx[le + i + 2], s3 = eidx[le + i + 3];
            float4 v0 = gs[(size_t)s0 * 4 + q], v1 = gs[(size_t)s1 * 4 + q];
            float4 v2 = gs[(size_t)s2 * 4 + q], v3 = gs[(size_t)s3 * 4 + q];
            a0.x += v0.x; a0.y += v0.y; a0.z += v0.z; a0.w += v0.w;
            a1.x += v1.x; a1.y += v1.y; a1.z += v1.z; a1.w += v1.w;
            a2.x += v2.x; a2.y += v2.y; a2.z += v2.z; a2.w += v2.w;
            a3.x += v3.x; a3.y += v3.y; a3.z += v3.z; a3.w += v3.w;
        }
        for (; i < m; ++i) {
            float4 v = gs[(size_t)eidx[le + i] * 4 + q];
            a0.x += v.x; a0.y += v.y; a0.z += v.z; a0.w += v.w;
        }
    } else {
        for (; i < m; ++i) {
            float4 v = gs[(size_t)csr_src[e0 + i] * 4 + q];
            a0.x += v.x; a0.y += v.y; a0.z += v.z; a0.w += v.w;
        }
    }
    a0.x += a1.x + a2.x + a3.x;
    a0.y += a1.y + a2.y + a3.y;
    a0.z += a1.z + a2.z + a3.z;
    a0.w += a1.w + a2.w + a3.w;

    const float* bf = bias + sl * 16 + q * 4;
    floatx4 r;
    r.x = fmaxf(dnode * a0.x + bf[0], 0.f);
    r.y = fmaxf(dnode * a0.y + bf[1], 0.f);
    r.z = fmaxf(dnode * a0.z + bf[2], 0.f);
    r.w = fmaxf(dnode * a0.w + bf[3], 0.f);
    floatx4* ob = reinterpret_cast<floatx4*>(outb);
    __builtin_nontemporal_store(r, &ob[((size_t)sl * n + node) * 4 + q]);
}

// ---------------- fp32 8-feature CSR aggregation (layer 5, writes d_out) ---
__global__ __launch_bounds__(256) void k_aggr8(const float4* __restrict__ gb,
                                               const int* __restrict__ offsets,
                                               const int* __restrict__ csr_src,
                                               const float* __restrict__ dinv,
                                               const float* __restrict__ bias,
                                               float4* __restrict__ outb, int n) {
    __shared__ int eidx[LDSE8];
    const int node0  = blockIdx.x * 128;
    const int nodeHi = (node0 + 128 < n) ? node0 + 128 : n;
    const int node   = node0 + (threadIdx.x >> 1);
    const int h      = threadIdx.x & 1;

    const int eS = offsets[node0];
    const int eE = offsets[nodeHi];
    const int C  = eE - eS;
    const bool useLds = (C <= LDSE8);

    const bool alive = (node < n);
    int e0 = 0, e1 = 0;
    float dnode = 0.f;
    float4 a0 = make_float4(0.f, 0.f, 0.f, 0.f);
    if (alive) {
        e0 = offsets[node];
        e1 = offsets[node + 1];
        dnode = dinv[node];
        a0 = gb[(size_t)node * 2 + h];            // self-loop term
    }

    if (useLds) {
        for (int i = threadIdx.x; i < C; i += 256)
            eidx[i] = __builtin_nontemporal_load(&csr_src[eS + i]);
    }
    __syncthreads();
    if (!alive) return;

    float4 a1 = make_float4(0.f, 0.f, 0.f, 0.f);
    float4 a2 = a1, a3 = a1;

    const int m = e1 - e0;
    int i = 0;
    if (useLds) {
        const int le = e0 - eS;
        for (; i + 4 <= m; i += 4) {
            int s0 = eidx[le + i + 0], s1 = eidx[le + i + 1];
            int s2 = eidx[le + i + 2], s3 = eidx[le + i + 3];
            float4 v0 = gb[(size_t)s0 * 2 + h], v1 = gb[(size_t)s1 * 2 + h];
            float4 v2 = gb[(size_t)s2 * 2 + h], v3 = gb[(size_t)s3 * 2 + h];
            a0.x += v0.x; a0.y += v0.y; a0.z += v0.z; a0.w += v0.w;
            a1.x += v1.x; a1.y += v1.y; a1.z += v1.z; a1.w += v1.w;
            a2.x += v2.x; a2.y += v2.y; a2.z += v2.z; a2.w += v2.w;
            a3.x += v3.x; a3.y += v3.y; a3.z += v3.z; a3.w += v3.w;
        }
        for (; i < m; ++i) {
            float4 v = gb[(size_t)eidx[le + i] * 2 + h];
            a0.x += v.x; a0.y += v.y; a0.z += v.z; a0.w += v.w;
        }
    } else {
        for (; i < m; ++i) {
            float4 v = gb[(size_t)csr_src[e0 + i] * 2 + h];
            a0.x += v.x; a0.y += v.y; a0.z += v.z; a0.w += v.w;
        }
    }
    a0.x += a1.x + a2.x + a3.x;
    a0.y += a1.y + a2.y + a3.y;
    a0.z += a1.z + a2.z + a3.z;
    a0.w += a1.w + a2.w + a3.w;

    const float* bf = bias + h * 4;
    floatx4 r;
    r.x = fmaxf(dnode * a0.x + bf[0], 0.f);
    r.y = fmaxf(dnode * a0.y + bf[1], 0.f);
    r.z = fmaxf(dnode * a0.z + bf[2], 0.f);
    r.w = fmaxf(dnode * a0.w + bf[3], 0.f);
    floatx4* ob = reinterpret_cast<floatx4*>(outb);
    __builtin_nontemporal_store(r, &ob[(size_t)node * 2 + h]);
}

extern "C" void kernel_launch(void* const* d_in, const int* in_sizes, int n_in,
                              void* d_out, int out_size, void* d_ws, size_t ws_size,
                              hipStream_t stream) {
    const int N = in_sizes[0] / 128;
    const int E = in_sizes[1] / 2;

    const float* x   = (const float*)d_in[0];
    const int*   ei  = (const int*)d_in[1];
    const int*   src = ei;
    const int*   dst = ei + E;
    const float* W1 = (const float*)d_in[2],  *b1 = (const float*)d_in[3];
    const float* W2 = (const float*)d_in[4],  *b2 = (const float*)d_in[5];
    const float* W3 = (const float*)d_in[6],  *b3 = (const float*)d_in[7];
    const float* W4 = (const float*)d_in[8],  *b4 = (const float*)d_in[9];
    const float* W5 = (const float*)d_in[10], *b5 = (const float*)d_in[11];
    float* out = (float*)d_out;

    size_t off = 0;
    auto alloc = [&](size_t bytes) {
        void* p = (char*)d_ws + off;
        off += (bytes + 255) & ~(size_t)255;
        return p;
    };
    int*   deg     = (int*)alloc((size_t)N * 4);
    int*   offsets = (int*)alloc((size_t)(N + 1) * 4);
    int*   cursor  = (int*)alloc((size_t)N * 4);
    int*   sums    = (int*)alloc(128 * 4);
    float* dinv    = (float*)alloc((size_t)N * 4);
    int*   csr_src = (int*)alloc((size_t)E * 4);
    float* g       = (float*)alloc((size_t)N * 128 * 4);
    float* xbuf    = (float*)alloc((size_t)N * 128 * 4);

    (void)hipMemsetAsync(deg, 0, (size_t)N * 4, stream);

    const int TB = 256;
    int nb   = (N + SCAN_B - 1) / SCAN_B;
    int nb16 = (N + 63) / 64;        // aggrh/aggr16: 64 nodes per block
    int nb8  = (N + 127) / 128;      // aggr8: 128 nodes per block
    const int RG = 2048;             // ranged kernels: 256 blocks per dst-range

    k_count_r<<<RG, TB, 0, stream>>>(dst, deg, E, N);
    k_scan_block<<<nb, SCAN_B, 0, stream>>>(deg, offsets, sums, N);
    k_scan_sums<<<1, 128, 0, stream>>>(sums, nb);
    k_finalize<<<(N + TB - 1) / TB, TB, 0, stream>>>(offsets, sums, deg, cursor, dinv, N, E);
    k_fill_r<<<RG, TB, 0, stream>>>(src, dst, cursor, csr_src, E, N);

    const float4* g4  = (const float4*)g;
    float4*       xb4 = (float4*)xbuf;

    // Layer 1: 128 -> 128  (fp16 g, 4 slice32s)
    k_gemm<128, 128, 8, 8, false, true><<<(N + 127) / 128, TB, 0, stream>>>(x, W1, dinv, g, N);
    k_aggrh<<<nb16 * 4, TB, 0, stream>>>(g4, offsets, csr_src, dinv, b1, xb4, N, 4);
    // Layer 2: 128 -> 64  (fp16 g, 2 slice32s)
    k_gemm<128, 64, 8, 8, true, true><<<(N + 255) / 256, TB, 0, stream>>>(xbuf, W2, dinv, g, N);
    k_aggrh<<<nb16 * 2, TB, 0, stream>>>(g4, offsets, csr_src, dinv, b2, xb4, N, 2);
    // Layer 3: 64 -> 32  (fp16 g, 1 slice32)
    k_gemm<64, 32, 8, 4, true, true><<<(N + 255) / 256, TB, 0, stream>>>(xbuf, W3, dinv, g, N);
    k_aggrh<<<nb16 * 1, TB, 0, stream>>>(g4, offsets, csr_src, dinv, b3, xb4, N, 1);
    // Layer 4: 32 -> 16  (fp32 g, 1 slice16)
    k_gemm<32, 16, 4, 4, true, false><<<(N + 255) / 256, TB, 0, stream>>>(xbuf, W4, dinv, g, N);
    k_aggr16<<<nb16 * 1, TB, 0, stream>>>(g4, offsets, csr_src, dinv, b4, xb4, N, 1);
    // Layer 5: 16 -> 8  (fp32 g row-major [n][8]; aggr8 writes d_out)
    k_gemm<16, 8, 4, 4, true, false><<<(N + 511) / 512, TB, 0, stream>>>(xbuf, W5, dinv, g, N);
    k_aggr8<<<nb8, TB, 0, stream>>>(g4, offsets, csr_src, dinv, b5, (float4*)out, N);
}